// Round 5
// baseline (241.365 us; speedup 1.0000x reference)
//
#include <hip/hip_runtime.h>
#include <stdint.h>

#define L_SEQ 8192
#define NCHUNK 64
#define CHUNK  128

typedef __attribute__((ext_vector_type(8))) short bf16x8;
typedef __attribute__((ext_vector_type(4))) float f32x4;

__device__ inline unsigned short f2bf(float x) {
  unsigned u = __builtin_bit_cast(unsigned, x);
  unsigned r = (u + 0x7fffu + ((u >> 16) & 1u)) >> 16;
  return (unsigned short)r;
}
__device__ inline float bf2f(unsigned short b) {
  unsigned u = ((unsigned)b) << 16;
  return __builtin_bit_cast(float, u);
}

#define GLD16(g, l)                                                            \
  __builtin_amdgcn_global_load_lds(                                            \
      (const __attribute__((address_space(1))) unsigned int*)(g),              \
      (__attribute__((address_space(3))) unsigned int*)(l), 16, 0, 0)

// ---------------------------------------------------------------------------
// Fused prep. Block-range dispatch (block-uniform branches):
//   [0,256)       Ft = F^T               (1024x256 bf16)
//   [256,512)     Ht = Hp^T
//   [512,1024)    T1 = E @ dP            (512x256 bf16)  block = row
//   [1024,2048)   T2 = G @ dR            (1024x256 bf16) block = row
//   [2048,2560)   Bim -> W1 odd rows (2p+1)
//   [2560,3584)   Cre/Cim -> Wy cols [1024,2048) interleaved (2Re,-2Im)
//   [3584,11776)  u -> A2 cols [0,1024)
// ---------------------------------------------------------------------------
__global__ __launch_bounds__(256) void prep(
    const float* __restrict__ F, const float* __restrict__ Hp,
    const float* __restrict__ dP, const float* __restrict__ dR,
    const float* __restrict__ E, const float* __restrict__ G,
    const float* __restrict__ Bim, const float* __restrict__ Cre,
    const float* __restrict__ Cim, const float* __restrict__ u,
    unsigned short* __restrict__ Ft, unsigned short* __restrict__ Ht,
    unsigned short* __restrict__ T1b, unsigned short* __restrict__ T2b,
    unsigned short* __restrict__ W1, unsigned short* __restrict__ Wy,
    unsigned short* __restrict__ A2) {
  __shared__ float tile[32][33];
  const int b = blockIdx.x, tid = threadIdx.x;
  if (b < 512) {  // transpose F (b<256) or Hp (b>=256)
    const float* src = (b < 256) ? F : Hp;
    unsigned short* dst = (b < 256) ? Ft : Ht;
    int bb = b & 255;
    int bx = bb & 31, by = bb >> 5;
    int tx = tid & 31, ty = tid >> 5;
#pragma unroll
    for (int dy = 0; dy < 32; dy += 8)
      tile[ty + dy][tx] = src[(size_t)(by * 32 + ty + dy) * 1024 + bx * 32 + tx];
    __syncthreads();
#pragma unroll
    for (int dy = 0; dy < 32; dy += 8)
      dst[(size_t)(bx * 32 + ty + dy) * 256 + by * 32 + tx] = f2bf(tile[tx][ty + dy]);
    return;
  }
  if (b < 1024) {  // T1 row i = E[i,:] @ dP
    int i = b - 512, j = tid;
    const float* Er = E + (size_t)i * 256;
    float acc = 0.f;
#pragma unroll 8
    for (int k = 0; k < 256; ++k) acc += Er[k] * dP[(size_t)k * 256 + j];
    T1b[(size_t)i * 256 + j] = f2bf(acc);
    return;
  }
  if (b < 2048) {  // T2 row i = G[i,:] @ dR
    int i = b - 1024, j = tid;
    const float* Gr = G + (size_t)i * 256;
    float acc = 0.f;
#pragma unroll 8
    for (int k = 0; k < 256; ++k) acc += Gr[k] * dR[(size_t)k * 256 + j];
    T2b[(size_t)i * 256 + j] = f2bf(acc);
    return;
  }
  if (b < 2560) {  // Bim row p -> W1 row 2p+1
    int q = (b - 2048) * 256 + tid;
    int e = q * 4, p = e >> 10, j = e & 1023;
    float4 v = *(const float4*)(Bim + (size_t)p * 1024 + j);
    ushort4 o = {f2bf(v.x), f2bf(v.y), f2bf(v.z), f2bf(v.w)};
    *(ushort4*)(W1 + (size_t)(2 * p + 1) * 1024 + j) = o;
    return;
  }
  if (b < 3584) {  // Cre/Cim -> Wy interleaved: col 1024+2p=2Re, 1025+2p=-2Im
    int q = (b - 2560) * 256 + tid;
    int i = q >> 8, jp = (q & 255) * 2;
    float2 re = *(const float2*)(Cre + (size_t)i * 512 + jp);
    float2 im = *(const float2*)(Cim + (size_t)i * 512 + jp);
    ushort4 o = {f2bf(2.f * re.x), f2bf(-2.f * im.x), f2bf(2.f * re.y), f2bf(-2.f * im.y)};
    *(ushort4*)(Wy + (size_t)i * 2048 + 1024 + 2 * jp) = o;
    return;
  }
  {  // u -> A2 cols [0,1024)
    int q = (b - 3584) * 256 + tid;
    int e = q * 4, i = e >> 10, j = e & 1023;
    float4 v = *(const float4*)(u + (size_t)i * 1024 + j);
    ushort4 o = {f2bf(v.x), f2bf(v.y), f2bf(v.z), f2bf(v.w)};
    *(ushort4*)(A2 + (size_t)i * 2048 + j) = o;
  }
}

// ---------------------------------------------------------------------------
// bf16 MFMA GEMM body: C(MxN) = A(MxK) @ B(NxK)^T [+ Add]
// 128x128 tile, 4 waves (2x2), global_load_lds staging.
// 3-buffer pipeline, counted vmcnt(4): 2 stages in flight, never drain to 0
// in the main loop; ONE barrier per K-step.
// ---------------------------------------------------------------------------
template <int HAS_ADD, int OUT_F32, int OUT_BF16>
__device__ __forceinline__ void gemm_body(
    const unsigned short* __restrict__ A, int lda,
    const unsigned short* __restrict__ B, int ldb,
    float* __restrict__ C, int ldc,
    unsigned short* __restrict__ Cb, int ldcb,
    const float* __restrict__ Add, int ldadd, int K, int m0, int n0,
    unsigned short* sA, unsigned short* sB) {
  const int tid = threadIdx.x;
  const int lane = tid & 63, wave = tid >> 6;
  const int wm = wave >> 1, wn = wave & 1;
  const int frow = lane & 15, fg = lane >> 4;

  // staging: wave w owns rows [w*32, w*32+32) of both tiles (two 16-row segs)
  const int srow = lane >> 2;
  const int scol = (lane & 3) * 8;
  const unsigned short* gA0 = A + (size_t)(m0 + wave * 32 + srow) * lda + scol;
  const unsigned short* gA1 = gA0 + (size_t)16 * lda;
  const unsigned short* gB0 = B + (size_t)(n0 + wave * 32 + srow) * ldb + scol;
  const unsigned short* gB1 = gB0 + (size_t)16 * ldb;

  f32x4 acc[4][4] = {};
  const int nt = K >> 5;

  auto STAGE = [&](int t, int buf) {
    const int kt = t * 32;
    unsigned short* a0 = sA + buf * 4096 + wave * 1024;
    unsigned short* b0 = sB + buf * 4096 + wave * 1024;
    GLD16(gA0 + kt, a0); GLD16(gA1 + kt, a0 + 512);
    GLD16(gB0 + kt, b0); GLD16(gB1 + kt, b0 + 512);
  };
  auto COMPUTE = [&](int buf) {
    const unsigned short* bA = sA + buf * 4096;
    const unsigned short* bB = sB + buf * 4096;
    bf16x8 fa[4], fb[4];
#pragma unroll
    for (int f = 0; f < 4; ++f) {
      fa[f] = *(const bf16x8*)(bA + (wm * 64 + f * 16 + frow) * 32 + fg * 8);
      fb[f] = *(const bf16x8*)(bB + (wn * 64 + f * 16 + frow) * 32 + fg * 8);
    }
#pragma unroll
    for (int i = 0; i < 4; ++i)
#pragma unroll
      for (int j = 0; j < 4; ++j)
        acc[i][j] = __builtin_amdgcn_mfma_f32_16x16x32_bf16(fa[i], fb[j], acc[i][j], 0, 0, 0);
  };

  // prologue: 2 stages in flight
  STAGE(0, 0);
  if (nt > 1) STAGE(1, 1);

  int buf = 0;
  for (int t = 0; t < nt - 1; ++t) {
    // my wave's oldest 4 VMEM ops (= stage t) retired; stage t+1 may fly on
    asm volatile("s_waitcnt vmcnt(4)" ::: "memory");
    __builtin_amdgcn_s_barrier();          // all waves' stage t landed
    __builtin_amdgcn_sched_barrier(0);
    if (t + 2 < nt) {
      int b2 = buf + 2; if (b2 >= 3) b2 -= 3;
      STAGE(t + 2, b2);
    }
    COMPUTE(buf);
    if (++buf == 3) buf = 0;
  }
  asm volatile("s_waitcnt vmcnt(0)" ::: "memory");
  __builtin_amdgcn_s_barrier();
  __builtin_amdgcn_sched_barrier(0);
  COMPUTE(buf);

  const int crow4 = (lane >> 4) * 4, ccol = lane & 15;
#pragma unroll
  for (int i = 0; i < 4; ++i)
#pragma unroll
    for (int j = 0; j < 4; ++j)
#pragma unroll
      for (int q = 0; q < 4; ++q) {
        int r = m0 + wm * 64 + i * 16 + crow4 + q;
        int c = n0 + wn * 64 + j * 16 + ccol;
        float v = acc[i][j][q];
        if (HAS_ADD) v += Add[(size_t)r * ldadd + c];
        if (OUT_F32) C[(size_t)r * ldc + c] = v;
        if (OUT_BF16) Cb[(size_t)r * ldcb + c] = f2bf(v);
      }
}

// Big GEMM with XCD-chunked swizzle (grid must be (64,8): nwg=512, 512%8==0).
template <int HAS_ADD, int OUT_F32, int OUT_BF16>
__global__ __launch_bounds__(256) void gemm_bt(
    const unsigned short* __restrict__ A, int lda,
    const unsigned short* __restrict__ B, int ldb,
    float* __restrict__ C, int ldc,
    unsigned short* __restrict__ Cb, int ldcb,
    const float* __restrict__ Add, int ldadd, int K) {
  __shared__ __align__(16) unsigned short sA[3 * 128 * 32];
  __shared__ __align__(16) unsigned short sB[3 * 128 * 32];
  // XCD swizzle: hardware round-robins linear wg id mod 8 across XCDs.
  // Give XCD x the m-tile stripe bx in [8x, 8x+8) over all n-tiles.
  int lin = blockIdx.y * gridDim.x + blockIdx.x;
  int xcd = lin & 7, idx = lin >> 3;
  int bx = xcd * 8 + (idx & 7);
  int by = idx >> 3;
  gemm_body<HAS_ADD, OUT_F32, OUT_BF16>(A, lda, B, ldb, C, ldc, Cb, ldcb, Add,
                                        ldadd, K, bx * 128, by * 128, sA, sB);
}

struct GemmP {
  const unsigned short* A; int lda;
  const unsigned short* B; int ldb;
  float* C; int ldc;
  unsigned short* Cb; int ldcb;
  const float* Add; int ldadd;
  int K; int gx;
};

template <int HAS_ADD, int OUT_F32, int OUT_BF16>
__global__ __launch_bounds__(256) void gemm_bt_dual(GemmP p0, GemmP p1) {
  __shared__ __align__(16) unsigned short sA[3 * 128 * 32];
  __shared__ __align__(16) unsigned short sB[3 * 128 * 32];
  GemmP p = blockIdx.z ? p1 : p0;
  if ((int)blockIdx.x >= p.gx) return;
  gemm_body<HAS_ADD, OUT_F32, OUT_BF16>(p.A, p.lda, p.B, p.ldb, p.C, p.ldc,
                                        p.Cb, p.ldcb, p.Add, p.ldadd, p.K,
                                        blockIdx.x * 128, blockIdx.y * 128, sA, sB);
}

// ---------------------------------------------------------------------------
// Scan phase 1: per (channel, chunk) local scan from 0; carry layout [c][p].
// Bub: row i, col 2p = re, 2p+1 = im (bf16).
// ---------------------------------------------------------------------------
__global__ __launch_bounds__(256) void scan_carry(const unsigned short* __restrict__ Bub,
                                                  const float* __restrict__ lre,
                                                  const float* __restrict__ lim,
                                                  float2* __restrict__ carry2) {
  int g = blockIdx.x * 256 + threadIdx.x;  // 0..32767
  int p = g & 511, c = g >> 9;
  float ar = lre[p], ai = lim[p];
  float sr = 0.f, si = 0.f;
  const unsigned short* base = Bub + (size_t)c * CHUNK * 1024 + 2 * p;
#pragma unroll 8
  for (int i = 0; i < CHUNK; ++i) {
    unsigned w = *(const unsigned*)(base + (size_t)i * 1024);
    float br = bf2f((unsigned short)(w & 0xffff));
    float bi = bf2f((unsigned short)(w >> 16));
    float nr = ar * sr - ai * si + br;
    float ni = ar * si + ai * sr + bi;
    sr = nr; si = ni;
  }
  carry2[(size_t)c * 512 + p] = make_float2(sr, si);
}

// ---------------------------------------------------------------------------
// Scan phase 2 (prefix inlined) + apply: each thread recomputes its chunk's
// carry-in from carry2 (c <= 63 coalesced loads), then re-scans and writes
// packed (re,im) bf16 into A2 cols [1024,2048).
// ---------------------------------------------------------------------------
__global__ __launch_bounds__(256) void scan_apply(const unsigned short* __restrict__ Bub,
                                                  const float* __restrict__ lre,
                                                  const float* __restrict__ lim,
                                                  const float2* __restrict__ carry2,
                                                  unsigned short* __restrict__ A2) {
  int g = blockIdx.x * 256 + threadIdx.x;
  int p = g & 511, c = g >> 9;  // c uniform per block
  float ar = lre[p], ai = lim[p];
  // lam^128 via 7 squarings
  float cr = ar, ci = ai;
#pragma unroll
  for (int s = 0; s < 7; ++s) {
    float t = cr * cr - ci * ci;
    ci = 2.f * cr * ci;
    cr = t;
  }
  // carry-in = scan of chunk carries 0..c-1
  float sr = 0.f, si = 0.f;
  for (int cc = 0; cc < c; ++cc) {
    float2 cv = carry2[(size_t)cc * 512 + p];
    float nr = cr * sr - ci * si + cv.x;
    float ni = cr * si + ci * sr + cv.y;
    sr = nr; si = ni;
  }
  const unsigned short* base = Bub + (size_t)c * CHUNK * 1024 + 2 * p;
  unsigned* ob = (unsigned*)(A2 + (size_t)c * CHUNK * 2048 + 1024 + 2 * p);
#pragma unroll 8
  for (int i = 0; i < CHUNK; ++i) {
    unsigned w = *(const unsigned*)(base + (size_t)i * 1024);
    float br = bf2f((unsigned short)(w & 0xffff));
    float bi = bf2f((unsigned short)(w >> 16));
    float nr = ar * sr - ai * si + br;
    float ni = ar * si + ai * sr + bi;
    sr = nr; si = ni;
    ob[(size_t)i * 1024] = (unsigned)f2bf(sr) | ((unsigned)f2bf(si) << 16);
  }
}

// ---------------------------------------------------------------------------
extern "C" void kernel_launch(void* const* d_in, const int* in_sizes, int n_in,
                              void* d_out, int out_size, void* d_ws, size_t ws_size,
                              hipStream_t stream) {
  const float* u   = (const float*)d_in[0];
  const float* F   = (const float*)d_in[1];
  const float* Hp  = (const float*)d_in[2];
  const float* dP  = (const float*)d_in[3];
  const float* dR  = (const float*)d_in[4];
  const float* E   = (const float*)d_in[5];
  const float* G   = (const float*)d_in[6];
  const float* lre = (const float*)d_in[7];
  const float* lim = (const float*)d_in[8];
  const float* Bre = (const float*)d_in[9];
  const float* Bim = (const float*)d_in[10];
  const float* Cre = (const float*)d_in[11];
  const float* Cim = (const float*)d_in[12];
  const float* Dm  = (const float*)d_in[13];
  float* y = (float*)d_out;

  uint8_t* ws = (uint8_t*)d_ws;
  size_t off = 0;
  auto alloc = [&](size_t bytes) {
    void* p = ws + off;
    off += (bytes + 255) & ~(size_t)255;
    return p;
  };
  unsigned short* A2  = (unsigned short*)alloc((size_t)L_SEQ * 2048 * 2);  // [u | x interleaved]
  unsigned short* W1  = (unsigned short*)alloc((size_t)1024 * 1024 * 2);   // rows 2p=B're, 2p+1=B'im
  unsigned short* Wy  = (unsigned short*)alloc((size_t)1024 * 2048 * 2);   // [D' | interleaved 2Cre/-2Cim]
  unsigned short* Bub = (unsigned short*)alloc((size_t)L_SEQ * 1024 * 2);  // bf16 interleaved
  unsigned short* Ft  = (unsigned short*)alloc((size_t)1024 * 256 * 2);
  unsigned short* Ht  = (unsigned short*)alloc((size_t)1024 * 256 * 2);
  unsigned short* T1b = (unsigned short*)alloc((size_t)512 * 256 * 2);
  unsigned short* T2b = (unsigned short*)alloc((size_t)1024 * 256 * 2);
  float* carry = (float*)alloc((size_t)NCHUNK * 512 * 8);
  (void)ws_size; (void)in_sizes; (void)n_in; (void)out_size;

  // 1) fused prep (includes T1 = E@dP, T2 = G@dR)
  prep<<<11776, 256, 0, stream>>>(F, Hp, dP, dR, E, G, Bim, Cre, Cim, u,
                                  Ft, Ht, T1b, T2b, W1, Wy, A2);

  // 2) W1 even rows = Bre + T1@Ft^T ; Wy[:,0:1024) = Dm + T2@Ht^T (paired)
  GemmP pc = {T1b, 256, Ft, 256, nullptr, 0, W1, 2048, Bre, 1024, 256, 4};
  GemmP pd = {T2b, 256, Ht, 256, nullptr, 0, Wy, 2048, Dm, 1024, 256, 8};
  gemm_bt_dual<1, 0, 1><<<dim3(8, 8, 2), 256, 0, stream>>>(pc, pd);

  // 3) Bu (bf16, interleaved) = u @ W1^T
  gemm_bt<0, 0, 1><<<dim3(64, 8), 256, 0, stream>>>(A2, 2048, W1, 1024, nullptr, 0,
                                                    Bub, 1024, nullptr, 0, 1024);

  // 4) scan
  scan_carry<<<128, 256, 0, stream>>>(Bub, lre, lim, (float2*)carry);
  scan_apply<<<128, 256, 0, stream>>>(Bub, lre, lim, (const float2*)carry, A2);

  // 5) y = [u | x] @ Wy^T
  gemm_bt<0, 1, 0><<<dim3(64, 8), 256, 0, stream>>>(A2, 2048, Wy, 2048, y, 1024,
                                                    nullptr, 0, nullptr, 0, 2048);
}

// Round 6
// 237.536 us; speedup vs baseline: 1.0161x; 1.0161x over previous
//
#include <hip/hip_runtime.h>
#include <stdint.h>

#define L_SEQ 8192
#define NCHUNK 128
#define CHUNK  64

typedef __attribute__((ext_vector_type(8))) short bf16x8;
typedef __attribute__((ext_vector_type(4))) float f32x4;

__device__ inline unsigned short f2bf(float x) {
  unsigned u = __builtin_bit_cast(unsigned, x);
  unsigned r = (u + 0x7fffu + ((u >> 16) & 1u)) >> 16;
  return (unsigned short)r;
}
__device__ inline float bf2f(unsigned short b) {
  unsigned u = ((unsigned)b) << 16;
  return __builtin_bit_cast(float, u);
}

#define GLD16(g, l)                                                            \
  __builtin_amdgcn_global_load_lds(                                            \
      (const __attribute__((address_space(1))) unsigned int*)(g),              \
      (__attribute__((address_space(3))) unsigned int*)(l), 16, 0, 0)

// ---------------------------------------------------------------------------
// Fused prep. Block-range dispatch (block-uniform branches):
//   [0,256)      Ft = F^T            (1024x256 bf16)
//   [256,512)    Ht = Hp^T
//   [512,576)    dPb cast            (256x256)
//   [576,640)    dRb cast
//   [640,768)    Eb cast             (512x256)
//   [768,1024)   Gb cast             (1024x256)
//   [1024,1536)  Bim -> W1 odd rows (2p+1)
//   [1536,2560)  Cre/Cim -> Wy cols [1024,2048) interleaved (2Re,-2Im)
//   [2560,10752) u -> A2 cols [0,1024)
// ---------------------------------------------------------------------------
__global__ __launch_bounds__(256) void prep(
    const float* __restrict__ F, const float* __restrict__ Hp,
    const float* __restrict__ dP, const float* __restrict__ dR,
    const float* __restrict__ E, const float* __restrict__ G,
    const float* __restrict__ Bim, const float* __restrict__ Cre,
    const float* __restrict__ Cim, const float* __restrict__ u,
    unsigned short* __restrict__ Ft, unsigned short* __restrict__ Ht,
    unsigned short* __restrict__ dPb, unsigned short* __restrict__ dRb,
    unsigned short* __restrict__ Eb, unsigned short* __restrict__ Gb,
    unsigned short* __restrict__ W1, unsigned short* __restrict__ Wy,
    unsigned short* __restrict__ A2) {
  __shared__ float tile[32][33];
  const int b = blockIdx.x, tid = threadIdx.x;
  if (b < 512) {  // transpose F (b<256) or Hp (b>=256)
    const float* src = (b < 256) ? F : Hp;
    unsigned short* dst = (b < 256) ? Ft : Ht;
    int bb = b & 255;
    int bx = bb & 31, by = bb >> 5;
    int tx = tid & 31, ty = tid >> 5;
#pragma unroll
    for (int dy = 0; dy < 32; dy += 8)
      tile[ty + dy][tx] = src[(size_t)(by * 32 + ty + dy) * 1024 + bx * 32 + tx];
    __syncthreads();
#pragma unroll
    for (int dy = 0; dy < 32; dy += 8)
      dst[(size_t)(bx * 32 + ty + dy) * 256 + by * 32 + tx] = f2bf(tile[tx][ty + dy]);
    return;
  }
  if (b < 1024) {  // flat casts
    const float* src;
    unsigned short* dst;
    int q;
    if (b < 576)      { src = dP; dst = dPb; q = (b - 512) * 256 + tid; }
    else if (b < 640) { src = dR; dst = dRb; q = (b - 576) * 256 + tid; }
    else if (b < 768) { src = E;  dst = Eb;  q = (b - 640) * 256 + tid; }
    else              { src = G;  dst = Gb;  q = (b - 768) * 256 + tid; }
    int e = q * 4;
    float4 v = *(const float4*)(src + e);
    ushort4 o = {f2bf(v.x), f2bf(v.y), f2bf(v.z), f2bf(v.w)};
    *(ushort4*)(dst + e) = o;
    return;
  }
  if (b < 1536) {  // Bim row p -> W1 row 2p+1
    int q = (b - 1024) * 256 + tid;
    int e = q * 4, p = e >> 10, j = e & 1023;
    float4 v = *(const float4*)(Bim + (size_t)p * 1024 + j);
    ushort4 o = {f2bf(v.x), f2bf(v.y), f2bf(v.z), f2bf(v.w)};
    *(ushort4*)(W1 + (size_t)(2 * p + 1) * 1024 + j) = o;
    return;
  }
  if (b < 2560) {  // Cre/Cim -> Wy interleaved: col 1024+2p=2Re, 1025+2p=-2Im
    int q = (b - 1536) * 256 + tid;
    int i = q >> 8, jp = (q & 255) * 2;
    float2 re = *(const float2*)(Cre + (size_t)i * 512 + jp);
    float2 im = *(const float2*)(Cim + (size_t)i * 512 + jp);
    ushort4 o = {f2bf(2.f * re.x), f2bf(-2.f * im.x), f2bf(2.f * re.y), f2bf(-2.f * im.y)};
    *(ushort4*)(Wy + (size_t)i * 2048 + 1024 + 2 * jp) = o;
    return;
  }
  {  // u -> A2 cols [0,1024)
    int q = (b - 2560) * 256 + tid;
    int e = q * 4, i = e >> 10, j = e & 1023;
    float4 v = *(const float4*)(u + (size_t)i * 1024 + j);
    ushort4 o = {f2bf(v.x), f2bf(v.y), f2bf(v.z), f2bf(v.w)};
    *(ushort4*)(A2 + (size_t)i * 2048 + j) = o;
  }
}

// ---------------------------------------------------------------------------
// bf16 MFMA GEMM body: C(MxN) = A(MxK) @ B(NxK)^T [+ Add]
// 128x128 tile, 4 waves (2x2), global_load_lds staging, DOUBLE-BUFFERED
// 2-phase: stage(t+1) issued before compute(t); ONE barrier per K-step.
// (R4-measured structure: 47us / 731 TF on K=2048.)
// TRANSB16: store bf16 output transposed (Cb[c*ldcb + r]).
// ---------------------------------------------------------------------------
template <int HAS_ADD, int OUT_F32, int OUT_BF16, int TRANSB16>
__device__ __forceinline__ void gemm_body(
    const unsigned short* __restrict__ A, int lda,
    const unsigned short* __restrict__ B, int ldb,
    float* __restrict__ C, int ldc,
    unsigned short* __restrict__ Cb, int ldcb,
    const float* __restrict__ Add, int ldadd, int K, int m0, int n0,
    unsigned short* sA, unsigned short* sB) {
  const int tid = threadIdx.x;
  const int lane = tid & 63, wave = tid >> 6;
  const int wm = wave >> 1, wn = wave & 1;
  const int frow = lane & 15, fg = lane >> 4;

  // staging: wave w owns rows [w*32, w*32+32) of both tiles (two 16-row segs)
  const int srow = lane >> 2;
  const int scol = (lane & 3) * 8;
  const unsigned short* gA0 = A + (size_t)(m0 + wave * 32 + srow) * lda + scol;
  const unsigned short* gA1 = gA0 + (size_t)16 * lda;
  const unsigned short* gB0 = B + (size_t)(n0 + wave * 32 + srow) * ldb + scol;
  const unsigned short* gB1 = gB0 + (size_t)16 * ldb;

  f32x4 acc[4][4] = {};
  const int nt = K >> 5;

  // prologue: stage tile 0 into buffer 0
  {
    unsigned short* a0 = sA + wave * 1024;
    unsigned short* b0 = sB + wave * 1024;
    GLD16(gA0, a0); GLD16(gA1, a0 + 512);
    GLD16(gB0, b0); GLD16(gB1, b0 + 512);
  }
  __syncthreads();

  for (int t = 0; t < nt; ++t) {
    const int cur = (t & 1) * 4096;
    if (t + 1 < nt) {  // stage next tile into other buffer
      const int nxt = 4096 - cur;
      const int kt = (t + 1) * 32;
      unsigned short* a0 = sA + nxt + wave * 1024;
      unsigned short* b0 = sB + nxt + wave * 1024;
      GLD16(gA0 + kt, a0); GLD16(gA1 + kt, a0 + 512);
      GLD16(gB0 + kt, b0); GLD16(gB1 + kt, b0 + 512);
    }
    const unsigned short* bA = sA + cur;
    const unsigned short* bB = sB + cur;
    bf16x8 fa[4], fb[4];
#pragma unroll
    for (int f = 0; f < 4; ++f) {
      fa[f] = *(const bf16x8*)(bA + (wm * 64 + f * 16 + frow) * 32 + fg * 8);
      fb[f] = *(const bf16x8*)(bB + (wn * 64 + f * 16 + frow) * 32 + fg * 8);
    }
#pragma unroll
    for (int i = 0; i < 4; ++i)
#pragma unroll
      for (int j = 0; j < 4; ++j)
        acc[i][j] = __builtin_amdgcn_mfma_f32_16x16x32_bf16(fa[i], fb[j], acc[i][j], 0, 0, 0);
    __syncthreads();  // drains vmcnt (stage t+1 done) + all reads of cur done
  }

  const int crow4 = (lane >> 4) * 4, ccol = lane & 15;
#pragma unroll
  for (int i = 0; i < 4; ++i)
#pragma unroll
    for (int j = 0; j < 4; ++j)
#pragma unroll
      for (int q = 0; q < 4; ++q) {
        int r = m0 + wm * 64 + i * 16 + crow4 + q;
        int c = n0 + wn * 64 + j * 16 + ccol;
        float v = acc[i][j][q];
        if (HAS_ADD) v += Add[(size_t)r * ldadd + c];
        if (OUT_F32) C[(size_t)r * ldc + c] = v;
        if (OUT_BF16) {
          if (TRANSB16) Cb[(size_t)c * ldcb + r] = f2bf(v);
          else          Cb[(size_t)r * ldcb + c] = f2bf(v);
        }
      }
}

template <int HAS_ADD, int OUT_F32, int OUT_BF16>
__global__ __launch_bounds__(256) void gemm_bt(
    const unsigned short* __restrict__ A, int lda,
    const unsigned short* __restrict__ B, int ldb,
    float* __restrict__ C, int ldc,
    unsigned short* __restrict__ Cb, int ldcb,
    const float* __restrict__ Add, int ldadd, int K) {
  __shared__ __align__(16) unsigned short sA[2 * 128 * 32];
  __shared__ __align__(16) unsigned short sB[2 * 128 * 32];
  gemm_body<HAS_ADD, OUT_F32, OUT_BF16, 0>(A, lda, B, ldb, C, ldc, Cb, ldcb,
                                           Add, ldadd, K, blockIdx.x * 128,
                                           blockIdx.y * 128, sA, sB);
}

struct GemmP {
  const unsigned short* A; int lda;
  const unsigned short* B; int ldb;
  float* C; int ldc;
  unsigned short* Cb; int ldcb;
  const float* Add; int ldadd;
  int K; int gx;
};

template <int HAS_ADD, int OUT_F32, int OUT_BF16, int TRANSB16>
__global__ __launch_bounds__(256) void gemm_bt_dual(GemmP p0, GemmP p1) {
  __shared__ __align__(16) unsigned short sA[2 * 128 * 32];
  __shared__ __align__(16) unsigned short sB[2 * 128 * 32];
  GemmP p = blockIdx.z ? p1 : p0;
  if ((int)blockIdx.x >= p.gx) return;
  gemm_body<HAS_ADD, OUT_F32, OUT_BF16, TRANSB16>(
      p.A, p.lda, p.B, p.ldb, p.C, p.ldc, p.Cb, p.ldcb, p.Add, p.ldadd, p.K,
      blockIdx.x * 128, blockIdx.y * 128, sA, sB);
}

// ---------------------------------------------------------------------------
// Scan phase 1: per (channel, chunk) local scan from 0; carry layout [c][p].
// Bub: row i, col 2p = re, 2p+1 = im (bf16). CHUNK=64 -> 65536 threads.
// ---------------------------------------------------------------------------
__global__ __launch_bounds__(256) void scan_carry(const unsigned short* __restrict__ Bub,
                                                  const float* __restrict__ lre,
                                                  const float* __restrict__ lim,
                                                  float2* __restrict__ carry2) {
  int g = blockIdx.x * 256 + threadIdx.x;  // 0..65535
  int p = g & 511, c = g >> 9;
  float ar = lre[p], ai = lim[p];
  float sr = 0.f, si = 0.f;
  const unsigned short* base = Bub + (size_t)c * CHUNK * 1024 + 2 * p;
#pragma unroll 8
  for (int i = 0; i < CHUNK; ++i) {
    unsigned w = *(const unsigned*)(base + (size_t)i * 1024);
    float br = bf2f((unsigned short)(w & 0xffff));
    float bi = bf2f((unsigned short)(w >> 16));
    float nr = ar * sr - ai * si + br;
    float ni = ar * si + ai * sr + bi;
    sr = nr; si = ni;
  }
  carry2[(size_t)c * 512 + p] = make_float2(sr, si);
}

// ---------------------------------------------------------------------------
// Scan phase 2 (prefix inlined) + apply: each thread recomputes its chunk's
// carry-in from carry2 (<=127 coalesced L2 loads), then re-scans and writes
// packed (re,im) bf16 into A2 cols [1024,2048).
// ---------------------------------------------------------------------------
__global__ __launch_bounds__(256) void scan_apply(const unsigned short* __restrict__ Bub,
                                                  const float* __restrict__ lre,
                                                  const float* __restrict__ lim,
                                                  const float2* __restrict__ carry2,
                                                  unsigned short* __restrict__ A2) {
  int g = blockIdx.x * 256 + threadIdx.x;
  int p = g & 511, c = g >> 9;  // c uniform per block
  float ar = lre[p], ai = lim[p];
  // lam^64 via 6 squarings
  float cr = ar, ci = ai;
#pragma unroll
  for (int s = 0; s < 6; ++s) {
    float t = cr * cr - ci * ci;
    ci = 2.f * cr * ci;
    cr = t;
  }
  // carry-in = scan of chunk carries 0..c-1
  float sr = 0.f, si = 0.f;
  for (int cc = 0; cc < c; ++cc) {
    float2 cv = carry2[(size_t)cc * 512 + p];
    float nr = cr * sr - ci * si + cv.x;
    float ni = cr * si + ci * sr + cv.y;
    sr = nr; si = ni;
  }
  const unsigned short* base = Bub + (size_t)c * CHUNK * 1024 + 2 * p;
  unsigned* ob = (unsigned*)(A2 + (size_t)c * CHUNK * 2048 + 1024 + 2 * p);
#pragma unroll 8
  for (int i = 0; i < CHUNK; ++i) {
    unsigned w = *(const unsigned*)(base + (size_t)i * 1024);
    float br = bf2f((unsigned short)(w & 0xffff));
    float bi = bf2f((unsigned short)(w >> 16));
    float nr = ar * sr - ai * si + br;
    float ni = ar * si + ai * sr + bi;
    sr = nr; si = ni;
    ob[(size_t)i * 1024] = (unsigned)f2bf(sr) | ((unsigned)f2bf(si) << 16);
  }
}

// ---------------------------------------------------------------------------
extern "C" void kernel_launch(void* const* d_in, const int* in_sizes, int n_in,
                              void* d_out, int out_size, void* d_ws, size_t ws_size,
                              hipStream_t stream) {
  const float* u   = (const float*)d_in[0];
  const float* F   = (const float*)d_in[1];
  const float* Hp  = (const float*)d_in[2];
  const float* dP  = (const float*)d_in[3];
  const float* dR  = (const float*)d_in[4];
  const float* E   = (const float*)d_in[5];
  const float* G   = (const float*)d_in[6];
  const float* lre = (const float*)d_in[7];
  const float* lim = (const float*)d_in[8];
  const float* Bre = (const float*)d_in[9];
  const float* Bim = (const float*)d_in[10];
  const float* Cre = (const float*)d_in[11];
  const float* Cim = (const float*)d_in[12];
  const float* Dm  = (const float*)d_in[13];
  float* y = (float*)d_out;

  uint8_t* ws = (uint8_t*)d_ws;
  size_t off = 0;
  auto alloc = [&](size_t bytes) {
    void* p = ws + off;
    off += (bytes + 255) & ~(size_t)255;
    return p;
  };
  unsigned short* A2  = (unsigned short*)alloc((size_t)L_SEQ * 2048 * 2);  // [u | x interleaved]
  unsigned short* W1  = (unsigned short*)alloc((size_t)1024 * 1024 * 2);   // rows 2p=B're, 2p+1=B'im
  unsigned short* Wy  = (unsigned short*)alloc((size_t)1024 * 2048 * 2);   // [D' | interleaved 2Cre/-2Cim]
  unsigned short* Bub = (unsigned short*)alloc((size_t)L_SEQ * 1024 * 2);  // bf16 interleaved
  unsigned short* Ft  = (unsigned short*)alloc((size_t)1024 * 256 * 2);
  unsigned short* Ht  = (unsigned short*)alloc((size_t)1024 * 256 * 2);
  unsigned short* S1t = (unsigned short*)alloc((size_t)1024 * 256 * 2);    // (dP@F)^T
  unsigned short* S2t = (unsigned short*)alloc((size_t)1024 * 256 * 2);    // (dR@Hp)^T
  unsigned short* dPb = (unsigned short*)alloc((size_t)256 * 256 * 2);
  unsigned short* dRb = (unsigned short*)alloc((size_t)256 * 256 * 2);
  unsigned short* Eb  = (unsigned short*)alloc((size_t)512 * 256 * 2);
  unsigned short* Gb  = (unsigned short*)alloc((size_t)1024 * 256 * 2);
  float* carry = (float*)alloc((size_t)NCHUNK * 512 * 8);
  (void)ws_size; (void)in_sizes; (void)n_in; (void)out_size;

  // 1) fused prep
  prep<<<10752, 256, 0, stream>>>(F, Hp, dP, dR, E, G, Bim, Cre, Cim, u,
                                  Ft, Ht, dPb, dRb, Eb, Gb, W1, Wy, A2);

  // 2) S1t = (dP@F)^T, S2t = (dR@Hp)^T  (transposed-store MFMA, paired)
  //    dP @ Ft^T = dP@F since Ft = F^T.
  GemmP pa = {dPb, 256, Ft, 256, nullptr, 0, S1t, 256, nullptr, 0, 256, 2};
  GemmP pb = {dRb, 256, Ht, 256, nullptr, 0, S2t, 256, nullptr, 0, 256, 2};
  gemm_bt_dual<0, 0, 1, 1><<<dim3(2, 8, 2), 256, 0, stream>>>(pa, pb);

  // 3) W1 even rows = Bre + E@S1t^T ; Wy[:,0:1024) = Dm + G@S2t^T (paired)
  GemmP pc = {Eb, 256, S1t, 256, nullptr, 0, W1, 2048, Bre, 1024, 256, 4};
  GemmP pd = {Gb, 256, S2t, 256, nullptr, 0, Wy, 2048, Dm, 1024, 256, 8};
  gemm_bt_dual<1, 0, 1, 0><<<dim3(8, 8, 2), 256, 0, stream>>>(pc, pd);

  // 4) Bu (bf16, interleaved) = u @ W1^T
  gemm_bt<0, 0, 1><<<dim3(64, 8), 256, 0, stream>>>(A2, 2048, W1, 1024, nullptr, 0,
                                                    Bub, 1024, nullptr, 0, 1024);

  // 5) scan
  scan_carry<<<256, 256, 0, stream>>>(Bub, lre, lim, (float2*)carry);
  scan_apply<<<256, 256, 0, stream>>>(Bub, lre, lim, (const float2*)carry, A2);

  // 6) y = [u | x] @ Wy^T
  gemm_bt<0, 1, 0><<<dim3(64, 8), 256, 0, stream>>>(A2, 2048, Wy, 2048, y, 1024,
                                                    nullptr, 0, nullptr, 0, 2048);
}